// Round 5
// baseline (265.333 us; speedup 1.0000x reference)
//
#include <hip/hip_runtime.h>

// 2-layer fused LSTM + linear head.  B=8192, T=128, D=32, H=64, gates=256.
// R5: 1024 thr (16 waves)/block, BT=16, grid 512 -> target 2 blocks/CU =
// 32 waves/CU (100% occ).  Wave wv owns ONE gate-interleaved row-tile per
// layer covering h in [4wv, 4wv+4):
//   A-row (lane bl): gate = bl&3, h = 4wv + (bl>>2)
//   D element r of lane (bl,kg): gate r of h = 4wv+kg  (all 4 gates/lane)
// Biases live in LDS (broadcast read) to fit the 64-VGPR / 8-wave-EU budget.
// log2e folded into weights (i,f,o x1.4427; g x2.8854); merged-rcp gate math
// = 7 trans/element.

#define TT  128
#define DIN 32
#define BT  16
#define L2E 1.44269504088896340736f

typedef _Float16 h8 __attribute__((ext_vector_type(8)));
typedef __fp16   p2 __attribute__((ext_vector_type(2)));
typedef float    f4 __attribute__((ext_vector_type(4)));

__device__ __forceinline__ h8 cvt8s(const float* p, float s) {
    float4 a = *(const float4*)p;
    float4 b = *(const float4*)(p + 4);
    union { h8 v; p2 q[4]; } u;
    u.q[0] = __builtin_amdgcn_cvt_pkrtz(a.x * s, a.y * s);
    u.q[1] = __builtin_amdgcn_cvt_pkrtz(a.z * s, a.w * s);
    u.q[2] = __builtin_amdgcn_cvt_pkrtz(b.x * s, b.y * s);
    u.q[3] = __builtin_amdgcn_cvt_pkrtz(b.z * s, b.w * s);
    return u.v;
}
__device__ __forceinline__ h8 cvt8(const float* p) {
    float4 a = *(const float4*)p;
    float4 b = *(const float4*)(p + 4);
    union { h8 v; p2 q[4]; } u;
    u.q[0] = __builtin_amdgcn_cvt_pkrtz(a.x, a.y);
    u.q[1] = __builtin_amdgcn_cvt_pkrtz(a.z, a.w);
    u.q[2] = __builtin_amdgcn_cvt_pkrtz(b.x, b.y);
    u.q[3] = __builtin_amdgcn_cvt_pkrtz(b.z, b.w);
    return u.v;
}

// acc = {yi', yf', yg'(2x-scaled), yo'} (log2e pre-folded); updates c, returns h.
__device__ __forceinline__ float elem(const f4& acc, float& c) {
    float Ei = __builtin_amdgcn_exp2f(-acc[0]);
    float Ef = __builtin_amdgcn_exp2f(-acc[1]);
    float Eg = __builtin_amdgcn_exp2f(-acc[2]);
    float Eo = __builtin_amdgcn_exp2f(-acc[3]);
    float a = 1.f + Ei, b = 1.f + Eg, d = 1.f + Ef;
    float P = a * b;
    float N = c * P + (1.f - Eg) * d;
    c = N * __builtin_amdgcn_rcpf(P * d);
    float Ec = __builtin_amdgcn_exp2f(-2.f * L2E * c);
    return (1.f - Ec) * __builtin_amdgcn_rcpf((1.f + Ec) * (1.f + Eo));
}

__global__ __launch_bounds__(1024, 8)
void lstm2_fused(const float* __restrict__ x,
                 const float* __restrict__ wih0, const float* __restrict__ whh0,
                 const float* __restrict__ bih0, const float* __restrict__ bhh0,
                 const float* __restrict__ wih1, const float* __restrict__ whh1,
                 const float* __restrict__ bih1, const float* __restrict__ bhh1,
                 const float* __restrict__ fcw,  const float* __restrict__ fcb,
                 float* __restrict__ out)
{
    const int tid  = threadIdx.x;
    const int lane = tid & 63;
    const int wv   = tid >> 6;      // 0..15 -> h slice [4wv, 4wv+4)
    const int bl   = lane & 15;
    const int kg   = lane >> 4;

    __shared__ alignas(16) unsigned short hb[2][2][BT * 64];  // 8 KB
    __shared__ alignas(16) float blds[2][64][4];              // 2 KB bias
    __shared__ float wpart[16][BT];                           // 1 KB

    for (int i = tid; i < (int)(sizeof(hb) / 4); i += 1024) ((int*)hb)[i] = 0;

    if (tid < 128) {   // biases -> LDS: blds[layer][4wv+kg][r] = (bih+bhh)[64r+4wv+kg]*sc
        const int layer = tid >> 6, idx = tid & 63;
        const int wvv = idx >> 2, kgg = idx & 3;
        const float* bi = layer ? bih1 : bih0;
        const float* bh = layer ? bhh1 : bhh0;
        #pragma unroll
        for (int r = 0; r < 4; ++r) {
            const int gr = 64 * r + 4 * wvv + kgg;
            const float scr = (r == 2) ? 2.f * L2E : L2E;
            blds[layer][idx][r] = (bi[gr] + bh[gr]) * scr;
        }
    }

    // ---- weights: one gate-interleaved tile per layer ----
    h8 W0[3], W1[4];
    {
        const int gam = bl & 3;
        const int g   = 64 * gam + 4 * wv + (bl >> 2);
        const float sc = (gam == 2) ? 2.f * L2E : L2E;
        W0[0] = cvt8s(wih0 + g * 32 + 8 * kg, sc);
        W0[1] = cvt8s(whh0 + g * 64 + 8 * kg, sc);
        W0[2] = cvt8s(whh0 + g * 64 + 32 + 8 * kg, sc);
        W1[0] = cvt8s(wih1 + g * 64 + 8 * kg, sc);
        W1[1] = cvt8s(wih1 + g * 64 + 32 + 8 * kg, sc);
        W1[2] = cvt8s(whh1 + g * 64 + 8 * kg, sc);
        W1[3] = cvt8s(whh1 + g * 64 + 32 + 8 * kg, sc);
    }

    const int bbase = blockIdx.x * BT;
    const float* xp = x + (size_t)(bbase + bl) * (TT * DIN) + 8 * kg;

    float c0 = 0.f, c1 = 0.f, h1f = 0.f;

    const int swz = (bl & 7) << 4;
    char* lb = (char*)hb;
    const int rowoff = bl * 128;
    const int rd0 = rowoff + ((16 * kg) ^ swz);
    const int rd1 = rowoff + ((64 + 16 * kg) ^ swz);
    const int wro = rowoff + ((8 * wv + 2 * kg) ^ swz);   // h = 4wv+kg (2B store)

    __syncthreads();   // LDS zero + biases visible

    const f4* bp0 = (const f4*)blds[0][4 * wv + kg];
    const f4* bp1 = (const f4*)blds[1][4 * wv + kg];

    auto L0 = [&](const h8& xc, const h8& hr0, const h8& hr1, int wp) {
        f4 acc = *bp0;
        acc = __builtin_amdgcn_mfma_f32_16x16x32_f16(W0[1], hr0, acc, 0, 0, 0);
        acc = __builtin_amdgcn_mfma_f32_16x16x32_f16(W0[2], hr1, acc, 0, 0, 0);
        acc = __builtin_amdgcn_mfma_f32_16x16x32_f16(W0[0], xc,  acc, 0, 0, 0);
        float h = elem(acc, c0);
        *(_Float16*)(lb + wp * 2048 + wro) = (_Float16)h;
    };

    auto L1 = [&](const h8& hr0, const h8& hr1, const h8& g1a, const h8& g1b,
                  int wp, bool store) {
        f4 acc = *bp1;
        acc = __builtin_amdgcn_mfma_f32_16x16x32_f16(W1[0], hr0, acc, 0, 0, 0);
        acc = __builtin_amdgcn_mfma_f32_16x16x32_f16(W1[1], hr1, acc, 0, 0, 0);
        acc = __builtin_amdgcn_mfma_f32_16x16x32_f16(W1[2], g1a, acc, 0, 0, 0);
        acc = __builtin_amdgcn_mfma_f32_16x16x32_f16(W1[3], g1b, acc, 0, 0, 0);
        float h = elem(acc, c1);
        h1f = h;
        if (store) *(_Float16*)(lb + 4096 + wp * 2048 + wro) = (_Float16)h;
    };

    // ---- it = 0: L0 only; h0[-1] = 0 from zeroed parity-1 buffer ----
    {
        h8 xc  = cvt8(xp);
        h8 hr0 = *(const h8*)(lb + 2048 + rd0);
        h8 hr1 = *(const h8*)(lb + 2048 + rd1);
        L0(xc, hr0, hr1, 0);
        __syncthreads();
    }

    // ---- it = 1..TT-1: L0(t=it) + L1(t=it-1), one barrier ----
    for (int it = 1; it < TT; ++it) {
        const int wp = it & 1, rp = wp ^ 1;
        h8 xc  = cvt8(xp + it * DIN);
        h8 hr0 = *(const h8*)(lb + rp * 2048 + rd0);          // h0[it-1]
        h8 hr1 = *(const h8*)(lb + rp * 2048 + rd1);
        h8 g1a = *(const h8*)(lb + 4096 + rp * 2048 + rd0);   // h1[it-2]
        h8 g1b = *(const h8*)(lb + 4096 + rp * 2048 + rd1);
        L0(xc, hr0, hr1, wp);
        L1(hr0, hr1, g1a, g1b, wp, true);
        __syncthreads();
    }

    // ---- tail: L1 for t = TT-1 ----
    {
        const int rp = 1;
        h8 hr0 = *(const h8*)(lb + rp * 2048 + rd0);          // h0[TT-1]
        h8 hr1 = *(const h8*)(lb + rp * 2048 + rd1);
        h8 g1a = *(const h8*)(lb + 4096 + rp * 2048 + rd0);   // h1[TT-2]
        h8 g1b = *(const h8*)(lb + 4096 + rp * 2048 + rd1);
        L1(hr0, hr1, g1a, g1b, 0, false);
    }

    // ---- head: out[b] = h1 . fc_w + fc_b ----
    float part = h1f * fcw[4 * wv + kg];
    part += __shfl_xor(part, 16, 64);
    part += __shfl_xor(part, 32, 64);
    if (lane < 16) wpart[wv][lane] = part;
    __syncthreads();
    if (tid < BT) {
        float s = fcb[0];
        #pragma unroll
        for (int w = 0; w < 16; ++w) s += wpart[w][tid];
        out[bbase + tid] = s;
    }
}

extern "C" void kernel_launch(void* const* d_in, const int* in_sizes, int n_in,
                              void* d_out, int out_size, void* d_ws, size_t ws_size,
                              hipStream_t stream) {
    (void)in_sizes; (void)n_in; (void)d_ws; (void)ws_size; (void)out_size;
    lstm2_fused<<<dim3(8192 / BT), dim3(1024), 0, stream>>>(
        (const float*)d_in[0],
        (const float*)d_in[1], (const float*)d_in[2],
        (const float*)d_in[3], (const float*)d_in[4],
        (const float*)d_in[5], (const float*)d_in[6],
        (const float*)d_in[7], (const float*)d_in[8],
        (const float*)d_in[9], (const float*)d_in[10],
        (float*)d_out);
}

// Round 6
// 184.914 us; speedup vs baseline: 1.4349x; 1.4349x over previous
//
#include <hip/hip_runtime.h>

// 2-layer fused LSTM + linear head.  B=8192, T=128, D=32, H=64, gates=256.
// R6 = R4 structure (512 thr / 8 waves, BT=16, grid 512) + x prefetch:
// next-iter global x loads issued at loop top, converted at loop end, so the
// ~200-900cy global latency hides under the iteration body (R3 had this;
// R4 dropped it and left a per-iter vmcnt stall).
// Wave wv owns h in [8wv, 8wv+8) as 2 row-tiles with GATE-INTERLEAVED rows:
//   tile row rho <-> weight row gate(rho&3), h = hbase + (rho>>2)
//   => D element r of lane (bl,kg) = gate r of h = hbase+kg  (all 4 gates/lane)
// log2e folded into weights (i,f,o x1.4427; g x2.8854); merged-rcp gate math:
//   7 trans/element.

#define TT  128
#define DIN 32
#define BT  16
#define L2E 1.44269504088896340736f

typedef _Float16 h8 __attribute__((ext_vector_type(8)));
typedef __fp16   p2 __attribute__((ext_vector_type(2)));
typedef float    f4 __attribute__((ext_vector_type(4)));

__device__ __forceinline__ h8 cvt8s(const float* p, float s) {
    float4 a = *(const float4*)p;
    float4 b = *(const float4*)(p + 4);
    union { h8 v; p2 q[4]; } u;
    u.q[0] = __builtin_amdgcn_cvt_pkrtz(a.x * s, a.y * s);
    u.q[1] = __builtin_amdgcn_cvt_pkrtz(a.z * s, a.w * s);
    u.q[2] = __builtin_amdgcn_cvt_pkrtz(b.x * s, b.y * s);
    u.q[3] = __builtin_amdgcn_cvt_pkrtz(b.z * s, b.w * s);
    return u.v;
}

__device__ __forceinline__ h8 pack8(const float4& a, const float4& b) {
    union { h8 v; p2 q[4]; } u;
    u.q[0] = __builtin_amdgcn_cvt_pkrtz(a.x, a.y);
    u.q[1] = __builtin_amdgcn_cvt_pkrtz(a.z, a.w);
    u.q[2] = __builtin_amdgcn_cvt_pkrtz(b.x, b.y);
    u.q[3] = __builtin_amdgcn_cvt_pkrtz(b.z, b.w);
    return u.v;
}

// acc = {yi', yf', yg'(2x-scaled), yo'} (log2e pre-folded); updates c, returns h.
__device__ __forceinline__ float elem(const f4& acc, float& c) {
    float Ei = __builtin_amdgcn_exp2f(-acc[0]);
    float Ef = __builtin_amdgcn_exp2f(-acc[1]);
    float Eg = __builtin_amdgcn_exp2f(-acc[2]);
    float Eo = __builtin_amdgcn_exp2f(-acc[3]);
    float a = 1.f + Ei, b = 1.f + Eg, d = 1.f + Ef;
    float P = a * b;
    float N = c * P + (1.f - Eg) * d;
    c = N * __builtin_amdgcn_rcpf(P * d);
    float Ec = __builtin_amdgcn_exp2f(-2.f * L2E * c);
    return (1.f - Ec) * __builtin_amdgcn_rcpf((1.f + Ec) * (1.f + Eo));
}

__global__ __launch_bounds__(512, 4)
void lstm2_fused(const float* __restrict__ x,
                 const float* __restrict__ wih0, const float* __restrict__ whh0,
                 const float* __restrict__ bih0, const float* __restrict__ bhh0,
                 const float* __restrict__ wih1, const float* __restrict__ whh1,
                 const float* __restrict__ bih1, const float* __restrict__ bhh1,
                 const float* __restrict__ fcw,  const float* __restrict__ fcb,
                 float* __restrict__ out)
{
    const int tid  = threadIdx.x;
    const int lane = tid & 63;
    const int wv   = tid >> 6;      // 0..7 -> h block 8*wv
    const int bl   = lane & 15;
    const int kg   = lane >> 4;

    __shared__ alignas(16) unsigned short hb[2][2][BT * 64];  // layer,parity,[b][h] f16
    __shared__ float wpart[8][BT];

    for (int i = tid; i < (int)(sizeof(hb) / 4); i += 512) ((int*)hb)[i] = 0;

    // ---- weights: gate-interleaved row tiles, log2e folded ----
    h8 W0[2][3], W1[2][4];
    f4 b0v[2], b1v[2];
    #pragma unroll
    for (int t = 0; t < 2; ++t) {
        const int hbse = 8 * wv + 4 * t;
        const int gam  = bl & 3;                         // gate of this A-row
        const int g    = 64 * gam + hbse + (bl >> 2);    // global weight row
        const float sc = (gam == 2) ? 2.f * L2E : L2E;
        W0[t][0] = cvt8s(wih0 + g * 32 + 8 * kg, sc);
        W0[t][1] = cvt8s(whh0 + g * 64 + 8 * kg, sc);
        W0[t][2] = cvt8s(whh0 + g * 64 + 32 + 8 * kg, sc);
        W1[t][0] = cvt8s(wih1 + g * 64 + 8 * kg, sc);
        W1[t][1] = cvt8s(wih1 + g * 64 + 32 + 8 * kg, sc);
        W1[t][2] = cvt8s(whh1 + g * 64 + 8 * kg, sc);
        W1[t][3] = cvt8s(whh1 + g * 64 + 32 + 8 * kg, sc);
        #pragma unroll
        for (int r = 0; r < 4; ++r) {
            const int gr = 64 * r + hbse + kg;           // D element r = gate r of h=hbse+kg
            const float scr = (r == 2) ? 2.f * L2E : L2E;
            b0v[t][r] = (bih0[gr] + bhh0[gr]) * scr;
            b1v[t][r] = (bih1[gr] + bhh1[gr]) * scr;
        }
    }

    const int bbase = blockIdx.x * BT;
    const float* xp = x + (size_t)(bbase + bl) * (TT * DIN) + 8 * kg;

    float c0[2] = {0.f, 0.f}, c1[2] = {0.f, 0.f}, h1f[2] = {0.f, 0.f};

    __syncthreads();   // LDS zero visible

    const int swz = (bl & 7) << 4;
    char* lb = (char*)hb;
    const int rowoff = bl * 128;
    const int rd0 = rowoff + ((16 * kg) ^ swz);
    const int rd1 = rowoff + ((64 + 16 * kg) ^ swz);
    const int wro0 = rowoff + ((16 * wv + 2 * kg) ^ swz);        // h = 8wv+kg   (t=0)
    const int wro1 = rowoff + ((16 * wv + 8 + 2 * kg) ^ swz);    // h = 8wv+4+kg (t=1)

    auto L0 = [&](const h8& xc, const h8& hr0, const h8& hr1, int wp) {
        #pragma unroll
        for (int t = 0; t < 2; ++t) {
            f4 acc = b0v[t];
            acc = __builtin_amdgcn_mfma_f32_16x16x32_f16(W0[t][1], hr0, acc, 0, 0, 0);
            acc = __builtin_amdgcn_mfma_f32_16x16x32_f16(W0[t][2], hr1, acc, 0, 0, 0);
            acc = __builtin_amdgcn_mfma_f32_16x16x32_f16(W0[t][0], xc,  acc, 0, 0, 0);
            float h = elem(acc, c0[t]);
            *(_Float16*)(lb + wp * 2048 + (t ? wro1 : wro0)) = (_Float16)h;
        }
    };

    auto L1 = [&](const h8& g0a, const h8& g0b, const h8& g1a, const h8& g1b,
                  int wp, bool store) {
        #pragma unroll
        for (int t = 0; t < 2; ++t) {
            f4 acc = b1v[t];
            acc = __builtin_amdgcn_mfma_f32_16x16x32_f16(W1[t][0], g0a, acc, 0, 0, 0);
            acc = __builtin_amdgcn_mfma_f32_16x16x32_f16(W1[t][1], g0b, acc, 0, 0, 0);
            acc = __builtin_amdgcn_mfma_f32_16x16x32_f16(W1[t][2], g1a, acc, 0, 0, 0);
            acc = __builtin_amdgcn_mfma_f32_16x16x32_f16(W1[t][3], g1b, acc, 0, 0, 0);
            float h = elem(acc, c1[t]);
            h1f[t] = h;
            if (store) *(_Float16*)(lb + 4096 + wp * 2048 + (t ? wro1 : wro0)) = (_Float16)h;
        }
    };

    h8 xcur;
    // ---- it = 0: L0 only (t=0); h0[-1]=0 from zeroed parity-1 buffer ----
    {
        float4 x0a = *(const float4*)(xp);
        float4 x0b = *(const float4*)(xp + 4);
        // prefetch x[1] before compute
        float4 xnA = *(const float4*)(xp + DIN);
        float4 xnB = *(const float4*)(xp + DIN + 4);
        h8 xc  = pack8(x0a, x0b);
        h8 hr0 = *(const h8*)(lb + 2048 + rd0);
        h8 hr1 = *(const h8*)(lb + 2048 + rd1);
        L0(xc, hr0, hr1, 0);
        xcur = pack8(xnA, xnB);
        __syncthreads();
    }

    // ---- it = 1..TT-1: L0(t=it) + L1(t=it-1), one barrier, x prefetched ----
    for (int it = 1; it < TT; ++it) {
        const int wp = it & 1, rp = wp ^ 1;
        // issue next-iter x loads FIRST (in flight across the whole body)
        const int tn = (it + 1 < TT) ? it + 1 : TT - 1;
        float4 xnA = *(const float4*)(xp + tn * DIN);
        float4 xnB = *(const float4*)(xp + tn * DIN + 4);

        h8 hr0 = *(const h8*)(lb + rp * 2048 + rd0);          // h0[it-1]
        h8 hr1 = *(const h8*)(lb + rp * 2048 + rd1);
        h8 g1a = *(const h8*)(lb + 4096 + rp * 2048 + rd0);   // h1[it-2]
        h8 g1b = *(const h8*)(lb + 4096 + rp * 2048 + rd1);

        L0(xcur, hr0, hr1, wp);
        L1(hr0, hr1, g1a, g1b, wp, true);

        xcur = pack8(xnA, xnB);   // vmcnt wait lands here, after all compute
        __syncthreads();
    }

    // ---- tail: L1 for t = TT-1 ----
    {
        const int rp = 1;   // TT even: last write parity
        h8 hr0 = *(const h8*)(lb + rp * 2048 + rd0);          // h0[TT-1]
        h8 hr1 = *(const h8*)(lb + rp * 2048 + rd1);
        h8 g1a = *(const h8*)(lb + 4096 + rp * 2048 + rd0);   // h1[TT-2]
        h8 g1b = *(const h8*)(lb + 4096 + rp * 2048 + rd1);
        L1(hr0, hr1, g1a, g1b, 0, false);
    }

    // ---- head: out[b] = h1 . fc_w + fc_b ----
    float part = h1f[0] * fcw[8 * wv + kg] + h1f[1] * fcw[8 * wv + 4 + kg];
    part += __shfl_xor(part, 16, 64);
    part += __shfl_xor(part, 32, 64);
    if (lane < 16) wpart[wv][lane] = part;
    __syncthreads();
    if (tid < BT) {
        float s = fcb[0];
        #pragma unroll
        for (int w = 0; w < 8; ++w) s += wpart[w][tid];
        out[bbase + tid] = s;
    }
}

extern "C" void kernel_launch(void* const* d_in, const int* in_sizes, int n_in,
                              void* d_out, int out_size, void* d_ws, size_t ws_size,
                              hipStream_t stream) {
    (void)in_sizes; (void)n_in; (void)d_ws; (void)ws_size; (void)out_size;
    lstm2_fused<<<dim3(8192 / BT), dim3(512), 0, stream>>>(
        (const float*)d_in[0],
        (const float*)d_in[1], (const float*)d_in[2],
        (const float*)d_in[3], (const float*)d_in[4],
        (const float*)d_in[5], (const float*)d_in[6],
        (const float*)d_in[7], (const float*)d_in[8],
        (const float*)d_in[9], (const float*)d_in[10],
        (float*)d_out);
}